// Round 3
// baseline (134.284 us; speedup 1.0000x reference)
//
#include <hip/hip_runtime.h>
#include <hip/hip_bf16.h>
#include <hip/hip_fp16.h>

// Problem constants
#define NT 8192            // tokens
#define NQB 6              // qubits
#define NL 2               // layers
// Attention kernel tiling
#define JSPLIT 16
#define JSLICE (NT / JSPLIT)     // 512 keys per block
#define CHUNK 32                 // keys staged per LDS chunk (one W-MFMA K-group)
#define NCHUNK (JSLICE / CHUNK)  // 16
#define IPW 16                   // query rows per wave (1 rowtile)
#define WPB 4                    // waves per block
#define IPB (IPW * WPB)          // 64 rows per block
#define NBI (NT / IPB)           // 128 i-blocks
#define WSTRIDE 40               // fp16 units per W-transpose row (80B: 16B-aligned, bank-spread)

typedef _Float16 f16x8 __attribute__((ext_vector_type(8)));
typedef float f32x4 __attribute__((ext_vector_type(4)));

static __device__ __forceinline__ unsigned int pack_h2(float a, float b) {
  unsigned short lo = __builtin_bit_cast(unsigned short, (_Float16)a);
  unsigned short hi = __builtin_bit_cast(unsigned short, (_Float16)b);
  return (unsigned int)lo | ((unsigned int)hi << 16);
}

static __device__ __forceinline__ unsigned int pkrtz(float a, float b) {
  return __builtin_bit_cast(unsigned int, __builtin_amdgcn_cvt_pkrtz(a, b));
}

// one CNOT's index map: src(p) = p ^ (bit_c(p) ? mask_t : 0)  (an involution)
static __device__ __forceinline__ int cnot_src(int p, int q) {
  const int mc = 1 << (5 - q);
  const int mt = 1 << (5 - ((q + 1) % NQB));
  return (p & mc) ? (p ^ mt) : p;
}

// direct-to-LDS 16B async copy (gfx950). LDS dest is wave-uniform base + lane*16.
#define GLOAD_LDS16(g, l)                                      \
  __builtin_amdgcn_global_load_lds(                            \
      (const __attribute__((address_space(1))) void*)(g),      \
      (__attribute__((address_space(3))) void*)(l), 16, 0, 0)

// ---------------------------------------------------------------------------
// Kernel 0: transcendental precompute. Kills ALL sincos in prep:
//  - xsc[tok*6+q]        = (sin(x/2), cos(x/2))      token data, shared by q/k/v
//  - phtab[set*128+lane]     = (cos phi0, sin phi0)  layer-0 RZ phase at m(lane)
//  - phtab[set*128+64+lane]  = (cos phi1, sin phi1)  layer-1 RZ phase at lane
//  - rytab[set*12+layer*6+q] = (sin(p/2), cos(p/2))  RY params
// ---------------------------------------------------------------------------
__global__ __launch_bounds__(256) void precomp_kernel(
    const float* __restrict__ x, const float* __restrict__ pq,
    const float* __restrict__ pk, const float* __restrict__ pv,
    float2* __restrict__ xsc, float2* __restrict__ phtab,
    float2* __restrict__ rytab)
{
  const int gid = blockIdx.x * 256 + threadIdx.x;
  if (gid < NT * NQB) {
    float s, c;
    __sincosf(0.5f * x[gid], &s, &c);
    xsc[gid] = make_float2(s, c);
    return;
  }
  const int t = gid - NT * NQB;
  if (t < 3 * 128) {
    const int set  = t >> 7;
    const int r    = t & 127;
    const int lane = r & 63;
    const int which = r >> 6;
    const float* pp = (set == 0) ? pq : ((set == 1) ? pk : pv);
    float phi = 0.f;
    if (which == 0) {
      int m = lane;
#pragma unroll
      for (int q = 5; q >= 0; --q) m = cnot_src(m, q);
#pragma unroll
      for (int q = 0; q < 6; ++q) {
        const float bh = 0.5f * pp[q * 2 + 1];
        phi += ((m >> (5 - q)) & 1) ? bh : -bh;
      }
    } else {
#pragma unroll
      for (int q = 0; q < 6; ++q) {
        const float bh = 0.5f * pp[12 + q * 2 + 1];
        phi += ((lane >> (5 - q)) & 1) ? bh : -bh;
      }
    }
    float s, c;
    __sincosf(phi, &s, &c);
    phtab[t] = make_float2(c, s);
  } else if (t < 3 * 128 + 36) {
    const int i = t - 3 * 128;
    const int set = i / 12, r = i % 12;      // r = layer*6 + q
    const float* pp = (set == 0) ? pq : ((set == 1) ? pk : pv);
    const int layer = r / 6, q = r % 6;
    float s, c;
    __sincosf(0.5f * pp[layer * 12 + q * 2], &s, &c);
    rytab[i] = make_float2(s, c);
  }
}

// ---------------------------------------------------------------------------
// Kernel 1: statevector prep — now sincos-free (tables from precomp_kernel).
// One wave per (token, set); lane = basis state. Outputs (fp16):
//  set0: Are linear  [tok][u32 e]
//  set1: Bk  uint4-XOR-preswizzled (u stored at u^(tok&15)) for conflict-free
//        swizzled ds_read after LINEAR global_load_lds staging in attn
//  set2: Vt [16][NT] fp16: rows 0..5 = <Z_q> hi, 6 = 1.0 (den), 7 = 0,
//        rows 8..13 = <Z_q> residual (lo), 14..15 = 0
// ---------------------------------------------------------------------------
__global__ __launch_bounds__(256) void prep_kernel(
    const float2* __restrict__ xsc, const float2* __restrict__ phtab,
    const float2* __restrict__ rytab,
    unsigned int* __restrict__ Are, unsigned int* __restrict__ Bk,
    unsigned short* __restrict__ Vt)
{
  const int wid  = blockIdx.x * 4 + (threadIdx.x >> 6);
  const int lane = threadIdx.x & 63;
  const int set  = wid >> 13;          // / 8192
  const int tok  = wid & (NT - 1);

  // sigma(l): product-state evaluation index; inv = sigma^{-1}(l)
  int m = lane;
#pragma unroll
  for (int q = 5; q >= 0; --q) m = cnot_src(m, q);
  int inv = lane;
#pragma unroll
  for (int q = 0; q < 6; ++q) inv = cnot_src(inv, q);

  const float2* xs = xsc + tok * NQB;
  const float2* ry = rytab + set * 12;

  // layer-0 RY magnitudes via angle addition: sincos(x/2 + p/2)
  float R = 1.f;
#pragma unroll
  for (int q = 0; q < 6; ++q) {
    const float2 tq = xs[q];     // (sin(x/2), cos(x/2))
    const float2 pr = ry[q];     // (sin(p/2), cos(p/2))
    const float s = tq.x * pr.y + tq.y * pr.x;
    const float c = tq.y * pr.y - tq.x * pr.x;
    R *= ((m >> (5 - q)) & 1) ? s : c;
  }
  // layer-0 RZ phase rotor (per-lane table)
  const float2 ph0 = phtab[set * 128 + lane];
  float re = R * ph0.x, im = R * ph0.y;

  // layer-1 RYs (entangled now -> shuffles); (s,c) wave-uniform from table
#pragma unroll
  for (int q = 0; q < 6; ++q) {
    const int mask = 1 << (5 - q);
    const float2 rc = ry[6 + q];
    const float pre = __shfl_xor(re, mask, 64);
    const float pim = __shfl_xor(im, mask, 64);
    const float se = (lane & mask) ? rc.x : -rc.x;
    re = fmaf(se, pre, rc.y * re);
    im = fmaf(se, pim, rc.y * im);
  }
  // layer-1 RZ phase rotor
  const float2 ph1 = phtab[set * 128 + 64 + lane];
  const float fre = re * ph1.x - im * ph1.y;
  const float fim = re * ph1.y + im * ph1.x;

  if (set == 0) {
    Are[tok * 64 + inv] = pack_h2(fre, fim);     // [qr, qi] fp16, linear
  } else if (set == 1) {
    const int sidx = ((((inv >> 2) ^ (tok & 15)) << 2) | (inv & 3));
    Bk[tok * 64 + sidx] = pack_h2(fre, fim);
  } else {
    const float prob = fre * fre + fim * fim;    // prob of final basis index 'inv'
    float vq[NQB];
#pragma unroll
    for (int q = 0; q < NQB; ++q) {
      float v = (inv & (1 << (5 - q))) ? -prob : prob;  // sign = 1-2*bit
#pragma unroll
      for (int off = 1; off < 64; off <<= 1) v += __shfl_xor(v, off, 64);
      vq[q] = v;
    }
    if (lane < 16) {
      const int q = lane & 7;
      float sel = vq[0];
      if (q == 1) sel = vq[1];
      if (q == 2) sel = vq[2];
      if (q == 3) sel = vq[3];
      if (q == 4) sel = vq[4];
      if (q == 5) sel = vq[5];
      if (q == 6) sel = 1.0f;                    // ones column -> den via MFMA
      if (q == 7) sel = 0.0f;
      float outv;
      if (lane < 8) {
        outv = sel;                              // hi part
      } else {
        const float hi = (float)(_Float16)sel;   // lo part = residual
        outv = (q < 6) ? (sel - hi) : 0.0f;
      }
      Vt[lane * NT + tok] = __builtin_bit_cast(unsigned short, (_Float16)outv);
    }
  }
}

// ---------------------------------------------------------------------------
// Kernel 2: fused swap-test attention, MFMA end-to-end.
//  - swapped QK^T: mfma(K, Q) so each lane's D regs = 4 consecutive keys for
//    one query row -> W transpose = 1 ds_write_b64 + 1 ds_read_b128 (per-wave).
//  - softmax num/den via second MFMA: acc = W(16x32) x [V|1|Vlo](32x16).
//  - single barrier per chunk (T3 minimum recipe): stage(c+1) issued at TOP
//    of iter c (in flight across the whole chunk's compute), own-wave
//    vmcnt(0) drain at BOTTOM, then one s_barrier certifying both "reads of
//    chunk c retired" and "everyone's stage(c+1) landed". 17 barriers vs 32.
//  - kbuf reads use the global preswizzle: per-lane offset ((s*4+quad)^col)*16.
// MFMA 16x16x32 layouts:
//   A/B: row/col = lane&15, k = (lane>>4)*8 + j;  D: col = lane&15, row = (lane>>4)*4 + r
// ---------------------------------------------------------------------------
__global__ __launch_bounds__(256, 2) void attn_kernel(
    const uint4* __restrict__ Are, const uint4* __restrict__ Bk,
    const unsigned short* __restrict__ Vt, float* __restrict__ part)
{
  __shared__ uint4 kbuf[2][CHUNK * 16];                           // 16 KiB, LINEAR dest
  __shared__ __align__(16) unsigned short wbuf[WPB][16][WSTRIDE]; // 5 KiB W transpose

  const int tid  = threadIdx.x;
  const int lane = tid & 63;
  const int wave = tid >> 6;
  const int col  = lane & 15;
  const int quad = lane >> 4;

  const int ib = blockIdx.x & (NBI - 1);
  const int js = blockIdx.x >> 7;                 // / NBI (NBI == 128)
  const int ibase = ib * IPB + wave * IPW;
  const int jbase0 = js * JSLICE;

  // Query fragments (MFMA B operand); qIm = (qi,-qr) derived per packed u32.
  f16x8 qRe[4], qIm[4];
  {
    const uint4* pr = Are + (ibase + col) * 16 + quad;
#pragma unroll
    for (int s = 0; s < 4; ++s) {
      const uint4 u = pr[s * 4];
      uint4 w;
      w.x = ((u.x << 16) | (u.x >> 16)) ^ 0x80000000u;
      w.y = ((u.y << 16) | (u.y >> 16)) ^ 0x80000000u;
      w.z = ((u.z << 16) | (u.z >> 16)) ^ 0x80000000u;
      w.w = ((u.w << 16) | (u.w >> 16)) ^ 0x80000000u;
      qRe[s] = __builtin_bit_cast(f16x8, u);
      qIm[s] = __builtin_bit_cast(f16x8, w);
    }
  }

  // per-lane swizzled kbuf byte offsets: u' = (s*4+quad) ^ col  (key&15 == col)
  int koff[4];
#pragma unroll
  for (int s = 0; s < 4; ++s) koff[s] = (((s * 4 + quad) ^ col) << 4);

  f32x4 acc = {0.f, 0.f, 0.f, 0.f};

  // stage chunk c (8 KiB = 32 keys x 256B) into kbuf[buf]: 2 x 1KiB per wave
  auto stage = [&](int buf, int c) {
#pragma unroll
    for (int r = 0; r < 2; ++r) {
      const int slot = wave * 2 + r;              // 0..7, 64 uint4 each
      GLOAD_LDS16(Bk + (size_t)(jbase0 + c * CHUNK) * 16 + slot * 64 + lane,
                  &kbuf[buf][slot * 64]);
    }
  };

  // prologue: stage chunk 0, drain own loads, barrier -> all waves' chunk 0 in LDS
  stage(0, 0);
  asm volatile("s_waitcnt vmcnt(0)" ::: "memory");
  __builtin_amdgcn_s_barrier();
  asm volatile("" ::: "memory");

#pragma unroll 1
  for (int c = 0; c < NCHUNK; ++c) {
    const int cur = c & 1;
    const int jb = jbase0 + c * CHUNK;
    // issue next chunk's stage at TOP: in flight across this chunk's compute.
    // Safe: buf(cur^1)'s previous readers (iter c-1) retired at the last barrier.
    if (c + 1 < NCHUNK) stage(cur ^ 1, c + 1);
    // V fragment for this 32-key group (B operand)
    const f16x8 vb = *(const f16x8*)(Vt + (size_t)col * NT + jb + quad * 8);

#pragma unroll
    for (int ct = 0; ct < 2; ++ct) {
      const char* kb = (const char*)kbuf[cur] + (ct * 16 + col) * 256;
      f16x8 bfr[4];
#pragma unroll
      for (int s = 0; s < 4; ++s) bfr[s] = *(const f16x8*)(kb + koff[s]);
      f32x4 aR = {0.f, 0.f, 0.f, 0.f};
      f32x4 aI = {0.f, 0.f, 0.f, 0.f};
#pragma unroll
      for (int s = 0; s < 4; ++s) {
        aR = __builtin_amdgcn_mfma_f32_16x16x32_f16(bfr[s], qRe[s], aR, 0, 0, 0);
        aI = __builtin_amdgcn_mfma_f32_16x16x32_f16(bfr[s], qIm[s], aI, 0, 0, 0);
      }
      // lane holds keys ct*16+quad*4..+3 for query row 'col'; f in [0,1]
      const float w0 = __expf(aR[0] * aR[0] + aI[0] * aI[0]);
      const float w1 = __expf(aR[1] * aR[1] + aI[1] * aI[1]);
      const float w2 = __expf(aR[2] * aR[2] + aI[2] * aI[2]);
      const float w3 = __expf(aR[3] * aR[3] + aI[3] * aI[3]);
      *(uint2*)&wbuf[wave][col][ct * 16 + quad * 4] =
          make_uint2(pkrtz(w0, w1), pkrtz(w2, w3));
    }
    // W-MFMA: A = W[qrow][key0..31], B = Vt[q][key0..31]  (per-wave, DS in-order)
    const f16x8 wA = *(const f16x8*)&wbuf[wave][col][quad * 8];
    acc = __builtin_amdgcn_mfma_f32_16x16x32_f16(wA, vb, acc, 0, 0, 0);

    if (c + 1 < NCHUNK) {
      // drain own stage(c+1) (had the whole chunk to land), then the single
      // barrier: reads of chunk c retired + everyone's stage(c+1) complete.
      asm volatile("s_waitcnt vmcnt(0)" ::: "memory");
      __builtin_amdgcn_s_barrier();
      asm volatile("" ::: "memory");
    }
  }

  // combine hi (cols 0..6) + lo (cols 8..14) and write partials
  float res[4];
#pragma unroll
  for (int r = 0; r < 4; ++r) res[r] = acc[r] + __shfl_xor(acc[r], 8, 64);
  if (col < 8) {
    float* p = part + ((size_t)(js * NT + ibase + quad * 4)) * 8 + col;
#pragma unroll
    for (int r = 0; r < 4; ++r) p[r * 8] = res[r];  // col6=den, col7=0
  }
}

// ---------------------------------------------------------------------------
// Kernel 3: combine the 16 j-slice partials, normalize, emit float32.
// ---------------------------------------------------------------------------
__global__ __launch_bounds__(256) void combine_kernel(
    const float* __restrict__ part, float* __restrict__ out)
{
  const int row = blockIdx.x * 256 + threadIdx.x;
  float acc[7] = {0.f, 0.f, 0.f, 0.f, 0.f, 0.f, 0.f};
#pragma unroll
  for (int js = 0; js < JSPLIT; ++js) {
    const float* p = part + ((size_t)(js * NT + row)) * 8;
#pragma unroll
    for (int q = 0; q < 7; ++q) acc[q] += p[q];
  }
  const float inv = 1.0f / acc[6];
#pragma unroll
  for (int q = 0; q < 6; ++q)
    out[row * 6 + q] = acc[q] * inv;
}

// ---------------------------------------------------------------------------
// Workspace layout (bytes):
//   Are  @ 0        : 8192*64*4 = 2 MiB   (fp16 pairs packed in u32, linear)
//   Bk   @ 2 MiB    : 2 MiB               (fp16 pairs, uint4-XOR-preswizzled)
//   Vt   @ 4 MiB    : 16*8192*2 = 256 KiB (fp16 [V|1|Vlo] rows)
//   part @ 4.25 MiB : 16*8192*8*4 = 4 MiB
//   xsc/phtab/rytab : OVERLAID on part (used by precomp+prep, dead before attn
//                     writes part): xsc 384 KiB @4.25MiB, phtab 3 KiB, rytab.
//   total 8.25 MiB
// ---------------------------------------------------------------------------
extern "C" void kernel_launch(void* const* d_in, const int* in_sizes, int n_in,
                              void* d_out, int out_size, void* d_ws, size_t ws_size,
                              hipStream_t stream) {
  const float* x  = (const float*)d_in[0];
  const float* pq = (const float*)d_in[1];
  const float* pk = (const float*)d_in[2];
  const float* pv = (const float*)d_in[3];
  char* ws = (char*)d_ws;
  unsigned int*   Are = (unsigned int*)(ws);
  unsigned int*   Bk  = (unsigned int*)(ws + (size_t)(2u << 20));
  unsigned short* Vt  = (unsigned short*)(ws + (size_t)(4u << 20));
  char*           partb = ws + (size_t)(4u << 20) + (size_t)(256u << 10);
  float*          prt = (float*)partb;
  float2*         xsc   = (float2*)partb;                          // overlay
  float2*         phtab = (float2*)(partb + (size_t)(384u << 10)); // overlay
  float2*         rytab = (float2*)(partb + (size_t)(384u << 10) + 4096);

  const int pre_grid = (NT * NQB + 3 * 128 + 36 + 255) / 256;      // 194
  precomp_kernel<<<pre_grid, 256, 0, stream>>>(x, pq, pk, pv, xsc, phtab, rytab);
  prep_kernel<<<(NT * 3) / 4, 256, 0, stream>>>(xsc, phtab, rytab, Are, Bk, Vt);
  attn_kernel<<<NBI * JSPLIT, 256, 0, stream>>>((const uint4*)Are, (const uint4*)Bk,
                                                Vt, prt);
  combine_kernel<<<NT / 256, 256, 0, stream>>>(prt, (float*)d_out);
}